// Round 9
// baseline (184.540 us; speedup 1.0000x reference)
//
#include <hip/hip_runtime.h>

#define NB 32
#define LL 2048
#define CH 512
#define BQ 512
#define HH 1024

typedef __attribute__((ext_vector_type(8))) short bf16x8;
typedef __attribute__((ext_vector_type(16))) float f32x16;

__device__ __forceinline__ unsigned int cvt_pk_bf16(float a, float b) {
  unsigned int r;
  asm("v_cvt_pk_bf16_f32 %0, %1, %2" : "=v"(r) : "v"(a), "v"(b));
  return r;   // lo16 = bf16(a), hi16 = bf16(b)
}

__device__ __forceinline__ float fast_tanh(float x) {
  float e = __builtin_amdgcn_exp2f(x * 2.885390081777927f);
  return 1.0f - 2.0f * __builtin_amdgcn_rcpf(e + 1.0f);
}

// ================ fused prep: pack ctx (A), pack Wc (B), res_qc ================
// bid <  2048          : pack 32 ctx rows -> apk[g][ks][lane] (A-frag order)
// 2048 <= bid < 2176   : pack Wc -> wcbp[cg][ks][lane] (B-frag order)
// 2176 <= bid < 2240   : res_qc[b][h] = query[b,:]·Wq[h,:] + bc[h]
__global__ __launch_bounds__(512) void k_prep(const float* __restrict__ ctx,
                                              uint4* __restrict__ apk,
                                              const float* __restrict__ Wc,
                                              uint4* __restrict__ wcbp,
                                              const float* __restrict__ query,
                                              const float* __restrict__ Wq,
                                              const float* __restrict__ bc,
                                              float* __restrict__ resqc) {
  int bid = blockIdx.x, t = threadIdx.x;
  if (bid < 2048) {
    int g = bid;
    int lane = t & 63, ksq = t >> 6;
    int lo = lane & 31, hi = lane >> 5;
    const float* rowp = ctx + (size_t)(g * 32 + lo) * CH + hi * 8;
    uint4* dst = apk + (size_t)g * 2048 + lane;
#pragma unroll
    for (int i = 0; i < 4; ++i) {
      int ks = ksq * 4 + i;
      const float4* s = (const float4*)(rowp + ks * 16);
      float4 v0 = s[0], v1 = s[1];
      uint4 p;
      p.x = cvt_pk_bf16(v0.x, v0.y);
      p.y = cvt_pk_bf16(v0.z, v0.w);
      p.z = cvt_pk_bf16(v1.x, v1.y);
      p.w = cvt_pk_bf16(v1.z, v1.w);
      dst[(size_t)ks * 64] = p;
    }
  } else if (bid < 2176) {
    int gid = (bid - 2048) * 512 + t;   // 65536 = 32 cg * 32 ks * 64 lanes
    int lane = gid & 63, ks = (gid >> 6) & 31, cg = gid >> 11;
    int lo = lane & 31, hi = lane >> 5;
    const float4* s = (const float4*)(Wc + (size_t)(cg * 32 + lo) * CH + hi * 8 + ks * 16);
    float4 v0 = s[0], v1 = s[1];
    uint4 p;
    p.x = cvt_pk_bf16(v0.x, v0.y);
    p.y = cvt_pk_bf16(v0.z, v0.w);
    p.z = cvt_pk_bf16(v1.x, v1.y);
    p.w = cvt_pk_bf16(v1.z, v1.w);
    wcbp[gid] = p;
  } else {
    int gid = (bid - 2176) * 512 + t;   // 32768
    int b = gid >> 10, h = gid & 1023;
    const float4* q4 = (const float4*)(query + (size_t)b * BQ);
    const float4* w4 = (const float4*)(Wq + (size_t)h * BQ);
    float acc = 0.f;
#pragma unroll 4
    for (int i = 0; i < BQ / 4; ++i) {
      float4 a = q4[i], w = w4[i];
      acc += a.x * w.x + a.y * w.y + a.z * w.z + a.w * w.w;
    }
    resqc[gid] = acc + bc[h];
  }
}

// ---------------- main GEMM+tanh+reduce: no LDS, no barriers ----------------
// 2048 blocks x 256 thr (4 waves). Block = 256 rows x 128 cols; wave = 64r x 128c
// acc[2][4] = 128 regs. Explicit 3-deep register pipeline (sA/sB slots, ks%3,
// fully unrolled -> static idx). SGPR bases (readfirstlane) + 1 VGPR offset.
__global__ __launch_bounds__(256, 2) void k_logits_pk(const uint4* __restrict__ apk,
                                                      const uint4* __restrict__ bpk,
                                                      const float* __restrict__ resqc,
                                                      const float* __restrict__ Wo,
                                                      float* __restrict__ logit) {
  int bid = blockIdx.x;
  // XCD swizzle: 8 cc-blocks of one rb land on one XCD -> A re-reads hit XCD-L2
  int xcd = bid & 7, idx = bid >> 3;
  int rb = xcd * 32 + (idx >> 3), cc = idx & 7;
  int t = threadIdx.x;
  int wv = t >> 6, lane = t & 63;
  int lo = lane & 31, hi = lane >> 5;
  int b = rb >> 3;

  int wvu = __builtin_amdgcn_readfirstlane(wv);
  const char* bA = (const char*)(apk + (size_t)(rb * 8 + wvu * 2) * 2048);
  const char* bB = (const char*)(bpk + (size_t)(cc * 4) * 2048);
  const int voff = lane * 16;

  uint4 sA[3][2], sB[3][4];
#pragma unroll
  for (int p = 0; p < 3; ++p) {
    sA[p][0] = *(const uint4*)(bA + voff + p * 1024);
    sA[p][1] = *(const uint4*)(bA + 32768 + voff + p * 1024);
#pragma unroll
    for (int n = 0; n < 4; ++n)
      sB[p][n] = *(const uint4*)(bB + (size_t)n * 32768 + voff + p * 1024);
  }
  int voff_i = voff + 3 * 1024;

  f32x16 acc[2][4];
#pragma unroll
  for (int m = 0; m < 2; ++m)
#pragma unroll
    for (int n = 0; n < 4; ++n) acc[m][n] = (f32x16){0,0,0,0,0,0,0,0,0,0,0,0,0,0,0,0};

#pragma unroll
  for (int ks = 0; ks < 32; ++ks) {
    const int sl = ks % 3;
    bf16x8 fa0, fa1, fb0, fb1, fb2, fb3;
    __builtin_memcpy(&fa0, &sA[sl][0], 16);
    __builtin_memcpy(&fa1, &sA[sl][1], 16);
    __builtin_memcpy(&fb0, &sB[sl][0], 16);
    __builtin_memcpy(&fb1, &sB[sl][1], 16);
    __builtin_memcpy(&fb2, &sB[sl][2], 16);
    __builtin_memcpy(&fb3, &sB[sl][3], 16);
    acc[0][0] = __builtin_amdgcn_mfma_f32_32x32x16_bf16(fa0, fb0, acc[0][0], 0, 0, 0);
    acc[0][1] = __builtin_amdgcn_mfma_f32_32x32x16_bf16(fa0, fb1, acc[0][1], 0, 0, 0);
    acc[0][2] = __builtin_amdgcn_mfma_f32_32x32x16_bf16(fa0, fb2, acc[0][2], 0, 0, 0);
    acc[0][3] = __builtin_amdgcn_mfma_f32_32x32x16_bf16(fa0, fb3, acc[0][3], 0, 0, 0);
    acc[1][0] = __builtin_amdgcn_mfma_f32_32x32x16_bf16(fa1, fb0, acc[1][0], 0, 0, 0);
    acc[1][1] = __builtin_amdgcn_mfma_f32_32x32x16_bf16(fa1, fb1, acc[1][1], 0, 0, 0);
    acc[1][2] = __builtin_amdgcn_mfma_f32_32x32x16_bf16(fa1, fb2, acc[1][2], 0, 0, 0);
    acc[1][3] = __builtin_amdgcn_mfma_f32_32x32x16_bf16(fa1, fb3, acc[1][3], 0, 0, 0);
    if (ks < 29) {
      sA[sl][0] = *(const uint4*)(bA + voff_i);
      sA[sl][1] = *(const uint4*)(bA + 32768 + voff_i);
#pragma unroll
      for (int n = 0; n < 4; ++n)
        sB[sl][n] = *(const uint4*)(bB + (size_t)n * 32768 + voff_i);
      voff_i += 1024;
    }
  }

  // epilogue: tanh + Wo-weighted col-sum -> 32 partials/lane, transpose-reduce
  float q_[4], wo_[4];
#pragma unroll
  for (int n = 0; n < 4; ++n) {
    q_[n]  = resqc[b * HH + cc * 128 + n * 32 + lo];
    wo_[n] = Wo[cc * 128 + n * 32 + lo];
  }
  float v[32];
#pragma unroll
  for (int m = 0; m < 2; ++m)
#pragma unroll
    for (int r = 0; r < 16; ++r) {
      float s = 0.f;
#pragma unroll
      for (int n = 0; n < 4; ++n) s += wo_[n] * fast_tanh(acc[m][n][r] + q_[n]);
      v[m * 16 + r] = s;
    }
#pragma unroll
  for (int sdist = 16; sdist >= 1; sdist >>= 1) {
#pragma unroll
    for (int i = 0; i < sdist; ++i) {
      float a = v[i], c = v[i + sdist];
      float keep = (lo & sdist) ? c : a;
      float send = (lo & sdist) ? a : c;
      v[i] = keep + __shfl_xor(send, sdist, 64);
    }
  }
  int rr = lo & 15;
  int row_local = (lo >> 4) * 32 + (rr & 3) + 8 * (rr >> 2) + 4 * hi;  // C/D row map
  int row = rb * 256 + wv * 64 + row_local;
  atomicAdd(&logit[row], v[0]);
}

// ---------------- weights: mask*exp(logit+bo), normalize over L ----------------
__global__ __launch_bounds__(256) void k_weights(const float* __restrict__ mask,
                                                 const float* __restrict__ bo,
                                                 const float* __restrict__ logit,
                                                 float* __restrict__ wout) {
  __shared__ float red[4];
  int b = blockIdx.x, t = threadIdx.x;
  float bov = bo[0];
  float w[8];
  float s = 0.f;
#pragma unroll
  for (int i = 0; i < 8; ++i) {
    int l = t + 256 * i;
    float e = mask[b * LL + l] * __expf(logit[b * LL + l] + bov);
    w[i] = e; s += e;
  }
#pragma unroll
  for (int m = 32; m >= 1; m >>= 1) s += __shfl_xor(s, m, 64);
  int wave = t >> 6, lane = t & 63;
  if (lane == 0) red[wave] = s;
  __syncthreads();
  float inv = 1.0f / (red[0] + red[1] + red[2] + red[3] + 1e-5f);
#pragma unroll
  for (int i = 0; i < 8; ++i) wout[b * LL + t + 256 * i] = w[i] * inv;
}

// ---------------- output from packed ctx: out[b][c] = sum_l w[b][l]*A[l][c] ----
// 512 blocks = 32 b x 4 ks-quarters x 4 L-chunks; 512 thr. Thread owns 16 cols,
// loops 16 tiles; shfl-reduce over lo; lane lo==0 atomicAdd (out zeroed).
__global__ __launch_bounds__(512) void k_output_pk(const uint4* __restrict__ apk,
                                                   const float* __restrict__ wout,
                                                   float* __restrict__ out) {
  int bid = blockIdx.x;
  int b = bid >> 4, q = (bid >> 2) & 3, lc = bid & 3;
  int t = threadIdx.x;
  int lane = t & 63, ks = q * 8 + (t >> 6);
  int lo = lane & 31, hi = lane >> 5;
  const uint4* pa = apk + (size_t)(b * 64 + lc * 16) * 2048 + (size_t)ks * 64 + lane;
  const float* wp = wout + b * LL + lc * 512 + lo;
  float a8[8] = {0,0,0,0,0,0,0,0};
#pragma unroll 4
  for (int gg = 0; gg < 16; ++gg) {
    uint4 u = pa[(size_t)gg * 2048];
    float w = wp[gg * 32];
    unsigned int uu[4] = {u.x, u.y, u.z, u.w};
#pragma unroll
    for (int j = 0; j < 4; ++j) {
      a8[2 * j]     += w * __uint_as_float(uu[j] << 16);
      a8[2 * j + 1] += w * __uint_as_float(uu[j] & 0xffff0000u);
    }
  }
#pragma unroll
  for (int m = 1; m <= 16; m <<= 1)
#pragma unroll
    for (int j = 0; j < 8; ++j) a8[j] += __shfl_xor(a8[j], m, 64);
  if (lo == 0) {
#pragma unroll
    for (int j = 0; j < 8; ++j) atomicAdd(&out[b * CH + ks * 16 + hi * 8 + j], a8[j]);
  }
}

// ================= fallback path (r6-proven) if ws too small ==========
__global__ __launch_bounds__(256) void k_resqc(const float* __restrict__ query,
                                               const float* __restrict__ Wq,
                                               const float* __restrict__ bc,
                                               float* __restrict__ resqc) {
  int gid = blockIdx.x * 256 + threadIdx.x;
  int b = gid >> 10, h = gid & 1023;
  const float4* q4 = (const float4*)(query + (size_t)b * BQ);
  const float4* w4 = (const float4*)(Wq + (size_t)h * BQ);
  float acc = 0.f;
#pragma unroll 4
  for (int i = 0; i < BQ / 4; ++i) {
    float4 a = q4[i], w = w4[i];
    acc += a.x * w.x + a.y * w.y + a.z * w.z + a.w * w.w;
  }
  resqc[gid] = acc + bc[h];
}

__global__ __launch_bounds__(256) void k_pack_wc(const float* __restrict__ Wc,
                                                 uint4* __restrict__ wcbp) {
  int gid = blockIdx.x * 256 + threadIdx.x;
  int lane = gid & 63, ks = (gid >> 6) & 31, cg = gid >> 11;
  int lo = lane & 31, hi = lane >> 5;
  const float4* s = (const float4*)(Wc + (size_t)(cg * 32 + lo) * CH + hi * 8 + ks * 16);
  float4 v0 = s[0], v1 = s[1];
  uint4 p;
  p.x = cvt_pk_bf16(v0.x, v0.y);
  p.y = cvt_pk_bf16(v0.z, v0.w);
  p.z = cvt_pk_bf16(v1.x, v1.y);
  p.w = cvt_pk_bf16(v1.z, v1.w);
  wcbp[gid] = p;
}

__global__ __launch_bounds__(512, 2) void k_logits_lds(const float* __restrict__ ctx,
                                                       const unsigned short* __restrict__ wcbp,
                                                       const float* __restrict__ resqc,
                                                       const float* __restrict__ Wo,
                                                       float* __restrict__ logits) {
  __shared__ unsigned short Alds[2][64 * 520];
  __shared__ float lsum4[4][64];
  const int t = threadIdx.x;
  const int g0 = blockIdx.x * 4;
  if (t < 256) lsum4[t >> 6][t & 63] = 0.f;
  {
    int b = g0 >> 5, row0 = (g0 & 31) << 6;
    const float4* src = (const float4*)(ctx + ((size_t)(b * LL + row0)) * CH);
#pragma unroll
    for (int i = 0; i < 16; ++i) {
      int f = i * 512 + t;
      int r = f >> 7, c4 = f & 127;
      float4 v = src[f];
      uint2 w;
      w.x = cvt_pk_bf16(v.x, v.y);
      w.y = cvt_pk_bf16(v.z, v.w);
      *(uint2*)(Alds[0] + r * 520 + c4 * 4) = w;
    }
  }
  __syncthreads();
  const int wave = t >> 6, lane = t & 63;
  const int lo = lane & 31, hi = lane >> 5;
  const int n0 = wave * 128;
  const uint4* bp = (const uint4*)wcbp + (size_t)(wave * 4) * 2048 + lane;
  float wo_[4];
#pragma unroll
  for (int n = 0; n < 4; ++n) wo_[n] = Wo[n0 + n * 32 + lo];
  for (int tt = 0; tt < 4; ++tt) {
    const int g = g0 + tt;
    const int b = g >> 5, row0 = (g & 31) << 6;
    const int cur = tt & 1;
    if (tt < 3) {
      int gn = g + 1;
      int nb = gn >> 5, nrow0 = (gn & 31) << 6;
      const float4* src = (const float4*)(ctx + ((size_t)(nb * LL + nrow0)) * CH);
#pragma unroll
      for (int i = 0; i < 16; ++i) {
        int f = i * 512 + t;
        int r = f >> 7, c4 = f & 127;
        float4 v = src[f];
        uint2 w;
        w.x = cvt_pk_bf16(v.x, v.y);
        w.y = cvt_pk_bf16(v.z, v.w);
        *(uint2*)(Alds[cur ^ 1] + r * 520 + c4 * 4) = w;
      }
    }
    const char* a0b = (const char*)(Alds[cur]) + lo * 1040 + hi * 16;
    f32x16 acc[2][4];
#pragma unroll
    for (int m = 0; m < 2; ++m)
#pragma unroll
      for (int n = 0; n < 4; ++n) acc[m][n] = (f32x16){0,0,0,0,0,0,0,0,0,0,0,0,0,0,0,0};
#pragma unroll 4
    for (int ks = 0; ks < 32; ++ks) {
      uint4 ub[4];
#pragma unroll
      for (int n = 0; n < 4; ++n) ub[n] = bp[(size_t)n * 2048 + ks * 64];
      bf16x8 fa[2];
#pragma unroll
      for (int m = 0; m < 2; ++m)
        fa[m] = *(const bf16x8*)(a0b + m * (32 * 1040) + ks * 32);
#pragma unroll
      for (int m = 0; m < 2; ++m)
#pragma unroll
        for (int n = 0; n < 4; ++n) {
          bf16x8 fb;
          __builtin_memcpy(&fb, &ub[n], 16);
          acc[m][n] = __builtin_amdgcn_mfma_f32_32x32x16_bf16(fa[m], fb, acc[m][n], 0, 0, 0);
        }
    }
    float q_[4];
#pragma unroll
    for (int n = 0; n < 4; ++n) q_[n] = resqc[b * HH + n0 + n * 32 + lo];
    float v[32];
#pragma unroll
    for (int m = 0; m < 2; ++m)
#pragma unroll
      for (int r = 0; r < 16; ++r) {
        float s = 0.f;
#pragma unroll
        for (int n = 0; n < 4; ++n) s += wo_[n] * fast_tanh(acc[m][n][r] + q_[n]);
        v[m * 16 + r] = s;
      }
#pragma unroll
    for (int sdist = 16; sdist >= 1; sdist >>= 1) {
#pragma unroll
      for (int i = 0; i < sdist; ++i) {
        float a = v[i], c = v[i + sdist];
        float keep = (lo & sdist) ? c : a;
        float send = (lo & sdist) ? a : c;
        v[i] = keep + __shfl_xor(send, sdist, 64);
      }
    }
    int rr = lo & 15;
    int row = ((lo < 16) ? 0 : 32) + (rr & 3) + 8 * (rr >> 2) + 4 * hi;
    atomicAdd(&lsum4[tt][row], v[0]);
    __syncthreads();
    if (t < 64) logits[(size_t)b * LL + row0 + t] = lsum4[tt][t];
  }
}

__global__ __launch_bounds__(256) void k_output_f32(const float* __restrict__ ctx,
                                                    const float* __restrict__ weights,
                                                    float* __restrict__ out) {
  __shared__ float wl[128];
  int bid = blockIdx.x;
  int b = bid >> 4, chunk = bid & 15;
  int t = threadIdx.x;
  int l0 = chunk * 128;
  if (t < 128) wl[t] = weights[b * LL + l0 + t];
  __syncthreads();
  const float2* c2 = (const float2*)(ctx + ((size_t)(b * LL + l0)) * CH) + t;
  float ax = 0.f, ay = 0.f;
#pragma unroll 4
  for (int l = 0; l < 128; ++l) {
    float wv = wl[l];
    float2 v = c2[(size_t)l * (CH / 2)];
    ax += wv * v.x; ay += wv * v.y;
  }
  atomicAdd(&out[b * CH + 2 * t], ax);
  atomicAdd(&out[b * CH + 2 * t + 1], ay);
}

extern "C" void kernel_launch(void* const* d_in, const int* in_sizes, int n_in,
                              void* d_out, int out_size, void* d_ws, size_t ws_size,
                              hipStream_t stream) {
  const float* query = (const float*)d_in[0];
  const float* ctx   = (const float*)d_in[1];
  const float* mask  = (const float*)d_in[2];
  const float* Wq    = (const float*)d_in[3];
  const float* Wc    = (const float*)d_in[4];
  const float* bc    = (const float*)d_in[5];
  const float* Wo    = (const float*)d_in[6];
  const float* bo    = (const float*)d_in[7];
  float* out = (float*)d_out;

  uint4* wcbp  = (uint4*)d_ws;                                    // 1 MB packed bf16 Wc
  float* resqc = (float*)((char*)d_ws + (1 << 20));               // 128 KB
  float* logit = (float*)((char*)d_ws + (1 << 20) + (1 << 17));   // 256 KB
  uint4* apk   = (uint4*)((char*)d_ws + (2 << 20));               // 64 MB packed bf16 ctx
  float* wout = out + NB * CH;                                    // final weights slot

  const size_t need = (size_t)(2 << 20) + ((size_t)64 << 20);

  if (ws_size >= need) {
    hipMemsetAsync(out, 0, NB * CH * sizeof(float), stream);
    hipMemsetAsync(logit, 0, NB * LL * sizeof(float), stream);
    k_prep<<<2240, 512, 0, stream>>>(ctx, apk, Wc, wcbp, query, Wq, bc, resqc);
    k_logits_pk<<<2048, 256, 0, stream>>>(apk, wcbp, resqc, Wo, logit);
    k_weights<<<32, 256, 0, stream>>>(mask, bo, logit, wout);
    k_output_pk<<<512, 512, 0, stream>>>(apk, wout, out);
  } else {
    hipMemsetAsync(out, 0, NB * CH * sizeof(float), stream);
    k_resqc<<<128, 256, 0, stream>>>(query, Wq, bc, resqc);
    k_pack_wc<<<256, 256, 0, stream>>>(Wc, wcbp);
    k_logits_lds<<<256, 512, 0, stream>>>(ctx, (const unsigned short*)wcbp, resqc, Wo, logit);
    k_weights<<<32, 256, 0, stream>>>(mask, bo, logit, wout);
    k_output_f32<<<512, 256, 0, stream>>>(ctx, wout, out);
  }
}

// Round 10
// 180.379 us; speedup vs baseline: 1.0231x; 1.0231x over previous
//
#include <hip/hip_runtime.h>

#define NB 32
#define LL 2048
#define CH 512
#define BQ 512
#define HH 1024

typedef __attribute__((ext_vector_type(8))) short bf16x8;
typedef __attribute__((ext_vector_type(16))) float f32x16;

__device__ __forceinline__ unsigned int cvt_pk_bf16(float a, float b) {
  unsigned int r;
  asm("v_cvt_pk_bf16_f32 %0, %1, %2" : "=v"(r) : "v"(a), "v"(b));
  return r;   // lo16 = bf16(a), hi16 = bf16(b)
}

__device__ __forceinline__ float fast_tanh(float x) {
  float e = __builtin_amdgcn_exp2f(x * 2.885390081777927f);
  return 1.0f - 2.0f * __builtin_amdgcn_rcpf(e + 1.0f);
}

// ---------------- res_qc[b][h] = query[b,:]·Wq[h,:] + bc[h] ----------------
__global__ __launch_bounds__(256) void k_resqc(const float* __restrict__ query,
                                               const float* __restrict__ Wq,
                                               const float* __restrict__ bc,
                                               float* __restrict__ resqc) {
  int gid = blockIdx.x * 256 + threadIdx.x;   // 32768
  int b = gid >> 10, h = gid & 1023;
  const float4* q4 = (const float4*)(query + (size_t)b * BQ);
  const float4* w4 = (const float4*)(Wq + (size_t)h * BQ);
  float acc = 0.f;
#pragma unroll 4
  for (int i = 0; i < BQ / 4; ++i) {
    float4 a = q4[i], w = w4[i];
    acc += a.x * w.x + a.y * w.y + a.z * w.z + a.w * w.w;
  }
  resqc[gid] = acc + bc[h];
}

// ---------------- Wc f32 -> bf16, packed in MFMA B-fragment order ----------------
// wcbp[cg][ksg][lane] : lane=(lo,hi) gets Wc[cg*32+lo][ksg*16 + hi*8 .. +8]
__global__ __launch_bounds__(256) void k_pack_wc(const float* __restrict__ Wc,
                                                 uint4* __restrict__ wcbp) {
  int gid = blockIdx.x * 256 + threadIdx.x;   // 65536 = 32 cg * 32 ks * 64 lanes
  int lane = gid & 63, ks = (gid >> 6) & 31, cg = gid >> 11;
  int lo = lane & 31, hi = lane >> 5;
  const float4* s = (const float4*)(Wc + (size_t)(cg * 32 + lo) * CH + hi * 8 + ks * 16);
  float4 v0 = s[0], v1 = s[1];
  uint4 p;
  p.x = cvt_pk_bf16(v0.x, v0.y);
  p.y = cvt_pk_bf16(v0.z, v0.w);
  p.z = cvt_pk_bf16(v1.x, v1.y);
  p.w = cvt_pk_bf16(v1.z, v1.w);
  wcbp[gid] = p;
}

// ---------------- main: 256x256 tile, BK=64, deep-pipelined, LDS frag-packed ----
// 1024 blocks x 512 thr (8 waves, 2M x 4N). Wave = 128r x 64c, acc[4][2]=128 AGPR.
// A: ctx f32 -> reg -> cvt_pk -> frag-packed LDS (conflict-free by construction).
// B: packed wcbp -> reg -> LDS. Raw s_barrier (no vmcnt(0) drain): kt+2 loads
// stay in flight across the barrier = the counted-vmcnt pipeline property.
__global__ __launch_bounds__(512, 2) void k_logits_8p(const float* __restrict__ ctx,
                                                      const uint4* __restrict__ bpk,
                                                      const float* __restrict__ resqc,
                                                      const float* __restrict__ Wo,
                                                      float* __restrict__ logit) {
  __shared__ char lds[131072];   // A: 2 x 32KB @0; B: 2 x 32KB @65536

  const int t = threadIdx.x;
  const int bid = blockIdx.x;
  const int mtile = (bid & 7) * 32 + (bid >> 5);   // XCD-bijective: xcd owns 32 M-tiles
  const int ntile = (bid >> 3) & 3;
  const int wv = t >> 6, lane = t & 63;
  const int wm = wv >> 2, wn = wv & 3;
  const int lo = lane & 31, hi = lane >> 5;
  const int b = mtile >> 3;
  const float* actx = ctx + (size_t)mtile * (256 * CH);

  // A staging map: 4 slot-writes/thread/K-step (256 rows x 8 slots of 8 k-elems)
  int arow[4], aoff[4];
#pragma unroll
  for (int w = 0; w < 4; ++w) {
    int sidx = w * 512 + t;
    int row = sidx >> 3, slot = sidx & 7;
    arow[w] = row * CH + slot * 8;                       // f32 offset in actx
    int rt = row >> 5, ks = slot >> 1, kh = slot & 1;
    aoff[w] = ((rt * 4 + ks) * 64 + ((row & 31) + 32 * kh)) * 16;
  }
  // B staging map: 4 loads/thread/K-step (8 cgs x 4 ks x 64 lanes)
  int bsrc[4], boff[4];
#pragma unroll
  for (int g = 0; g < 4; ++g) {
    int fidx = g * 512 + t;
    int cgi = fidx >> 8, ksl = (fidx >> 6) & 3, bl = fidx & 63;
    bsrc[g] = ((ntile * 8 + cgi) * 32 + ksl) * 64 + bl;  // uint4 index, + kt*256/step
    boff[g] = fidx * 16;
  }

  float4 av[8]; uint4 bv[4];

  // ---- prologue: stage K-step 0 into slot 0; issue K-step 1 loads ----
#pragma unroll
  for (int w = 0; w < 4; ++w) {
    const float4* s = (const float4*)(actx + arow[w]);
    av[2 * w] = s[0]; av[2 * w + 1] = s[1];
  }
#pragma unroll
  for (int g = 0; g < 4; ++g) bv[g] = bpk[bsrc[g]];
#pragma unroll
  for (int w = 0; w < 4; ++w) {
    uint4 pk;
    pk.x = cvt_pk_bf16(av[2 * w].x, av[2 * w].y);
    pk.y = cvt_pk_bf16(av[2 * w].z, av[2 * w].w);
    pk.z = cvt_pk_bf16(av[2 * w + 1].x, av[2 * w + 1].y);
    pk.w = cvt_pk_bf16(av[2 * w + 1].z, av[2 * w + 1].w);
    *(uint4*)(lds + aoff[w]) = pk;
  }
#pragma unroll
  for (int g = 0; g < 4; ++g) *(uint4*)(lds + 65536 + boff[g]) = bv[g];
#pragma unroll
  for (int w = 0; w < 4; ++w) {
    const float4* s = (const float4*)(actx + arow[w] + 64);
    av[2 * w] = s[0]; av[2 * w + 1] = s[1];
  }
#pragma unroll
  for (int g = 0; g < 4; ++g) bv[g] = bpk[bsrc[g] + 256];
  asm volatile("s_waitcnt lgkmcnt(0)" ::: "memory");
  __builtin_amdgcn_sched_barrier(0);
  __builtin_amdgcn_s_barrier();
  __builtin_amdgcn_sched_barrier(0);

  f32x16 acc[4][2];
#pragma unroll
  for (int m = 0; m < 4; ++m)
#pragma unroll
    for (int n = 0; n < 2; ++n) acc[m][n] = (f32x16){0,0,0,0,0,0,0,0,0,0,0,0,0,0,0,0};

  for (int kt = 0; kt < 8; ++kt) {
    char* Ap = lds + ((kt & 1) << 15);
    char* Bp = lds + 65536 + ((kt & 1) << 15);
    char* An = lds + (((kt & 1) ^ 1) << 15);
    char* Bn = lds + 65536 + (((kt & 1) ^ 1) << 15);

    // phase 1: compute ks 0,1 from buf p
    __builtin_amdgcn_s_setprio(1);
#pragma unroll
    for (int ks = 0; ks < 2; ++ks) {
      bf16x8 fb0 = *(const bf16x8*)(Bp + (((wn * 2 + 0) * 4 + ks) * 64 + lane) * 16);
      bf16x8 fb1 = *(const bf16x8*)(Bp + (((wn * 2 + 1) * 4 + ks) * 64 + lane) * 16);
#pragma unroll
      for (int m = 0; m < 4; ++m) {
        bf16x8 fa = *(const bf16x8*)(Ap + (((wm * 4 + m) * 4 + ks) * 64 + lane) * 16);
        acc[m][0] = __builtin_amdgcn_mfma_f32_32x32x16_bf16(fa, fb0, acc[m][0], 0, 0, 0);
        acc[m][1] = __builtin_amdgcn_mfma_f32_32x32x16_bf16(fa, fb1, acc[m][1], 0, 0, 0);
      }
    }
    __builtin_amdgcn_s_setprio(0);
    __builtin_amdgcn_sched_barrier(0);

    // phase 2: write staged K-step kt+1 into buf p^1
    if (kt < 7) {
#pragma unroll
      for (int w = 0; w < 4; ++w) {
        uint4 pk;
        pk.x = cvt_pk_bf16(av[2 * w].x, av[2 * w].y);
        pk.y = cvt_pk_bf16(av[2 * w].z, av[2 * w].w);
        pk.z = cvt_pk_bf16(av[2 * w + 1].x, av[2 * w + 1].y);
        pk.w = cvt_pk_bf16(av[2 * w + 1].z, av[2 * w + 1].w);
        *(uint4*)(An + aoff[w]) = pk;
      }
#pragma unroll
      for (int g = 0; g < 4; ++g) *(uint4*)(Bn + boff[g]) = bv[g];
    }
    __builtin_amdgcn_sched_barrier(0);

    // phase 3: issue loads for K-step kt+2 (consumed next iter; cross the barrier)
    if (kt < 6) {
#pragma unroll
      for (int w = 0; w < 4; ++w) {
        const float4* s = (const float4*)(actx + arow[w] + (kt + 2) * 64);
        av[2 * w] = s[0]; av[2 * w + 1] = s[1];
      }
#pragma unroll
      for (int g = 0; g < 4; ++g) bv[g] = bpk[bsrc[g] + (kt + 2) * 256];
    }
    __builtin_amdgcn_sched_barrier(0);

    // phase 4: compute ks 2,3 from buf p
    __builtin_amdgcn_s_setprio(1);
#pragma unroll
    for (int ks = 2; ks < 4; ++ks) {
      bf16x8 fb0 = *(const bf16x8*)(Bp + (((wn * 2 + 0) * 4 + ks) * 64 + lane) * 16);
      bf16x8 fb1 = *(const bf16x8*)(Bp + (((wn * 2 + 1) * 4 + ks) * 64 + lane) * 16);
#pragma unroll
      for (int m = 0; m < 4; ++m) {
        bf16x8 fa = *(const bf16x8*)(Ap + (((wm * 4 + m) * 4 + ks) * 64 + lane) * 16);
        acc[m][0] = __builtin_amdgcn_mfma_f32_32x32x16_bf16(fa, fb0, acc[m][0], 0, 0, 0);
        acc[m][1] = __builtin_amdgcn_mfma_f32_32x32x16_bf16(fa, fb1, acc[m][1], 0, 0, 0);
      }
    }
    __builtin_amdgcn_s_setprio(0);
    __builtin_amdgcn_sched_barrier(0);

    // phase 5: raw barrier — ds ops drained, vm loads stay in flight
    if (kt < 7) {
      asm volatile("s_waitcnt lgkmcnt(0)" ::: "memory");
      __builtin_amdgcn_sched_barrier(0);
      __builtin_amdgcn_s_barrier();
      __builtin_amdgcn_sched_barrier(0);
    }
  }

  // epilogue: tanh + Wo col-sum, transpose-reduce over 32 col-lanes, global atomics
  const int c0 = ntile * 256 + wn * 64;
  float q0 = resqc[b * HH + c0 + lo], q1 = resqc[b * HH + c0 + 32 + lo];
  float w0 = Wo[c0 + lo],             w1 = Wo[c0 + 32 + lo];
#pragma unroll
  for (int rp = 0; rp < 2; ++rp) {
    float v[32];
#pragma unroll
    for (int mm = 0; mm < 2; ++mm)
#pragma unroll
      for (int r = 0; r < 16; ++r)
        v[mm * 16 + r] = w0 * fast_tanh(acc[rp * 2 + mm][0][r] + q0)
                       + w1 * fast_tanh(acc[rp * 2 + mm][1][r] + q1);
#pragma unroll
    for (int sdist = 16; sdist >= 1; sdist >>= 1) {
#pragma unroll
      for (int i = 0; i < sdist; ++i) {
        float a = v[i], c = v[i + sdist];
        float keep = (lo & sdist) ? c : a;
        float send = (lo & sdist) ? a : c;
        v[i] = keep + __shfl_xor(send, sdist, 64);
      }
    }
    int rr = lo & 15;
    int m = rp * 2 + (lo >> 4);
    int grow = mtile * 256 + wm * 128 + m * 32 + (rr & 3) + 8 * (rr >> 2) + 4 * hi;
    atomicAdd(&logit[grow], v[0]);
  }
}

// ---------------- weights: mask*exp(logit+bo), normalize over L ----------------
__global__ __launch_bounds__(256) void k_weights(const float* __restrict__ mask,
                                                 const float* __restrict__ bo,
                                                 const float* __restrict__ logit,
                                                 float* __restrict__ wout) {
  __shared__ float red[4];
  int b = blockIdx.x, t = threadIdx.x;
  float bov = bo[0];
  float w[8];
  float s = 0.f;
#pragma unroll
  for (int i = 0; i < 8; ++i) {
    int l = t + 256 * i;
    float e = mask[b * LL + l] * __expf(logit[b * LL + l] + bov);
    w[i] = e; s += e;
  }
#pragma unroll
  for (int m = 32; m >= 1; m >>= 1) s += __shfl_xor(s, m, 64);
  int wave = t >> 6, lane = t & 63;
  if (lane == 0) red[wave] = s;
  __syncthreads();
  float inv = 1.0f / (red[0] + red[1] + red[2] + red[3] + 1e-5f);
#pragma unroll
  for (int i = 0; i < 8; ++i) wout[b * LL + t + 256 * i] = w[i] * inv;
}

// ---------------- output[b][c] = sum_l weights[b][l] * ctx[b][l][c] ----------------
__global__ __launch_bounds__(256) void k_output_f32(const float* __restrict__ ctx,
                                                    const float* __restrict__ weights,
                                                    float* __restrict__ out) {
  __shared__ float wl[128];
  int bid = blockIdx.x;            // 512 = 32 b * 16 chunks
  int b = bid >> 4, chunk = bid & 15;
  int t = threadIdx.x;
  int l0 = chunk * 128;
  if (t < 128) wl[t] = weights[b * LL + l0 + t];
  __syncthreads();
  const float2* c2 = (const float2*)(ctx + ((size_t)(b * LL + l0)) * CH) + t;
  float ax = 0.f, ay = 0.f;
#pragma unroll 4
  for (int l = 0; l < 128; ++l) {
    float wv = wl[l];
    float2 v = c2[(size_t)l * (CH / 2)];
    ax += wv * v.x; ay += wv * v.y;
  }
  atomicAdd(&out[b * CH + 2 * t], ax);
  atomicAdd(&out[b * CH + 2 * t + 1], ay);
}

extern "C" void kernel_launch(void* const* d_in, const int* in_sizes, int n_in,
                              void* d_out, int out_size, void* d_ws, size_t ws_size,
                              hipStream_t stream) {
  const float* query = (const float*)d_in[0];
  const float* ctx   = (const float*)d_in[1];
  const float* mask  = (const float*)d_in[2];
  const float* Wq    = (const float*)d_in[3];
  const float* Wc    = (const float*)d_in[4];
  const float* bc    = (const float*)d_in[5];
  const float* Wo    = (const float*)d_in[6];
  const float* bo    = (const float*)d_in[7];
  float* out = (float*)d_out;

  uint4* wcbp  = (uint4*)d_ws;                                    // 1 MB packed bf16 Wc
  float* resqc = (float*)((char*)d_ws + (1 << 20));               // 128 KB
  float* logit = (float*)((char*)d_ws + (1 << 20) + (1 << 17));   // 256 KB
  float* wout = out + NB * CH;                                    // final weights slot

  hipMemsetAsync(out, 0, NB * CH * sizeof(float), stream);
  hipMemsetAsync(logit, 0, NB * LL * sizeof(float), stream);
  k_resqc<<<128, 256, 0, stream>>>(query, Wq, bc, resqc);
  k_pack_wc<<<256, 256, 0, stream>>>(Wc, wcbp);
  k_logits_8p<<<1024, 512, 0, stream>>>(ctx, wcbp, resqc, Wo, logit);
  k_weights<<<32, 256, 0, stream>>>(mask, bo, logit, wout);
  k_output_f32<<<512, 256, 0, stream>>>(ctx, wout, out);
}

// Round 11
// 157.467 us; speedup vs baseline: 1.1719x; 1.1455x over previous
//
#include <hip/hip_runtime.h>

#define NB 32
#define LL 2048
#define CH 512
#define BQ 512
#define HH 1024

typedef __attribute__((ext_vector_type(8))) short bf16x8;
typedef __attribute__((ext_vector_type(16))) float f32x16;

__device__ __forceinline__ unsigned int cvt_pk_bf16(float a, float b) {
  unsigned int r;
  asm("v_cvt_pk_bf16_f32 %0, %1, %2" : "=v"(r) : "v"(a), "v"(b));
  return r;   // lo16 = bf16(a), hi16 = bf16(b)
}

__device__ __forceinline__ float fast_tanh(float x) {
  float e = __builtin_amdgcn_exp2f(x * 2.885390081777927f);
  return 1.0f - 2.0f * __builtin_amdgcn_rcpf(e + 1.0f);
}

// ---------------- res_qc[b][h] = query[b,:]·Wq[h,:] + bc[h] ----------------
__global__ __launch_bounds__(256) void k_resqc(const float* __restrict__ query,
                                               const float* __restrict__ Wq,
                                               const float* __restrict__ bc,
                                               float* __restrict__ resqc) {
  int gid = blockIdx.x * 256 + threadIdx.x;   // 32768
  int b = gid >> 10, h = gid & 1023;
  const float4* q4 = (const float4*)(query + (size_t)b * BQ);
  const float4* w4 = (const float4*)(Wq + (size_t)h * BQ);
  float acc = 0.f;
#pragma unroll 4
  for (int i = 0; i < BQ / 4; ++i) {
    float4 a = q4[i], w = w4[i];
    acc += a.x * w.x + a.y * w.y + a.z * w.z + a.w * w.w;
  }
  resqc[gid] = acc + bc[h];
}

// ---------------- Wc f32 -> bf16, packed in MFMA B-fragment order ----------------
// wcbp[cg][ks][lane] : lane=(lo,hi) gets Wc[cg*32+lo][ks*16 + hi*8 .. +8]
__global__ __launch_bounds__(256) void k_pack_wc(const float* __restrict__ Wc,
                                                 uint4* __restrict__ wcbp) {
  int gid = blockIdx.x * 256 + threadIdx.x;   // 65536 = 32 cg * 32 ks * 64 lanes
  int lane = gid & 63, ks = (gid >> 6) & 31, cg = gid >> 11;
  int lo = lane & 31, hi = lane >> 5;
  const float4* s = (const float4*)(Wc + (size_t)(cg * 32 + lo) * CH + hi * 8 + ks * 16);
  float4 v0 = s[0], v1 = s[1];
  uint4 p;
  p.x = cvt_pk_bf16(v0.x, v0.y);
  p.y = cvt_pk_bf16(v0.z, v0.w);
  p.z = cvt_pk_bf16(v1.x, v1.y);
  p.w = cvt_pk_bf16(v1.z, v1.w);
  wcbp[gid] = p;
}

// ---------------- ctx f32 -> bf16 A-frag pack via LDS transpose ----------------
// Both global sides coalesced. LDS: 32 rows x 520 bf16 (1040 B rows: 16B-aligned,
// ~2-way banks on b128 reads = free). One 32-row tile per block.
__global__ __launch_bounds__(256) void k_pack_ctx_t(const float* __restrict__ ctx,
                                                    uint4* __restrict__ apk) {
  __shared__ unsigned short slds[32 * 520];   // 33280 B
  int g = blockIdx.x;              // 2048 tiles
  int t = threadIdx.x;
  const float4* src = (const float4*)(ctx + (size_t)g * 32 * CH);
  // phase 1: coalesced f32 read -> cvt -> LDS rows (b64 writes)
#pragma unroll
  for (int i = 0; i < 16; ++i) {
    int f = i * 256 + t;           // 4096 float4s
    int row = f >> 7, c4 = f & 127;
    float4 v = src[f];
    uint2 w;
    w.x = cvt_pk_bf16(v.x, v.y);
    w.y = cvt_pk_bf16(v.z, v.w);
    *(uint2*)(slds + row * 520 + c4 * 4) = w;
  }
  __syncthreads();
  // phase 2: read frag chunks (contiguous 8 bf16 per lane) -> coalesced write
  uint4* dst = apk + (size_t)g * 2048;
#pragma unroll
  for (int i = 0; i < 8; ++i) {
    int idx2 = i * 256 + t;        // 2048 chunks = 32 ks x 64 lanes
    int ks = idx2 >> 6, lane2 = idx2 & 63;
    int lo = lane2 & 31, hi = lane2 >> 5;
    uint4 u = *(const uint4*)(slds + lo * 520 + ks * 16 + hi * 8);
    dst[idx2] = u;
  }
}

// ---------------- main GEMM+tanh+reduce: no LDS, no barriers, 3 waves/SIMD ----
// 4096 blocks x 256 thr (4 waves, 2M x 2N). Block = 128 rows x 128 cols; wave =
// 64r x 64c, acc[2][2] = 64 AGPR -> ~145 total regs -> 3 waves/SIMD (vs r8's 2).
// A,B pre-packed -> all loads coalesced 1KB/wave; compiler pipelines the loop.
__global__ __launch_bounds__(256, 3) void k_logits_pk3(const uint4* __restrict__ apk,
                                                       const uint4* __restrict__ bpk,
                                                       const float* __restrict__ resqc,
                                                       const float* __restrict__ Wo,
                                                       float* __restrict__ logit) {
  int bid = blockIdx.x;
  // XCD swizzle (4096%8==0, bijective): xcd owns 64 row-blocks; the 8 cc-chunks
  // of one rb are consecutive -> A tile stays hot in the XCD L2.
  int xcd = bid & 7, idx = bid >> 3;
  int rb = xcd * 64 + (idx >> 3);  // 512 row-blocks of 128 rows
  int cc = idx & 7;                // 8 col-chunks of 128
  int t = threadIdx.x;
  int wv = t >> 6, lane = t & 63;
  int wm = wv >> 1, wn = wv & 1;
  int lo = lane & 31, hi = lane >> 5;
  int b = rb >> 4;

  const uint4* pa0 = apk + (size_t)(rb * 4 + wm * 2) * 2048 + lane;
  const uint4* pa1 = pa0 + 2048;
  const uint4* pb0 = bpk + (size_t)(cc * 4 + wn * 2) * 2048 + lane;
  const uint4* pb1 = pb0 + 2048;

  f32x16 acc[2][2];
#pragma unroll
  for (int m = 0; m < 2; ++m)
#pragma unroll
    for (int n = 0; n < 2; ++n) acc[m][n] = (f32x16){0,0,0,0,0,0,0,0,0,0,0,0,0,0,0,0};

#pragma unroll 4
  for (int ks = 0; ks < 32; ++ks) {
    uint4 ua0 = pa0[(size_t)ks * 64];
    uint4 ua1 = pa1[(size_t)ks * 64];
    uint4 ub0 = pb0[(size_t)ks * 64];
    uint4 ub1 = pb1[(size_t)ks * 64];
    bf16x8 fa0, fa1, fb0, fb1;
    __builtin_memcpy(&fa0, &ua0, 16);
    __builtin_memcpy(&fa1, &ua1, 16);
    __builtin_memcpy(&fb0, &ub0, 16);
    __builtin_memcpy(&fb1, &ub1, 16);
    acc[0][0] = __builtin_amdgcn_mfma_f32_32x32x16_bf16(fa0, fb0, acc[0][0], 0, 0, 0);
    acc[0][1] = __builtin_amdgcn_mfma_f32_32x32x16_bf16(fa0, fb1, acc[0][1], 0, 0, 0);
    acc[1][0] = __builtin_amdgcn_mfma_f32_32x32x16_bf16(fa1, fb0, acc[1][0], 0, 0, 0);
    acc[1][1] = __builtin_amdgcn_mfma_f32_32x32x16_bf16(fa1, fb1, acc[1][1], 0, 0, 0);
  }

  // epilogue: tanh + Wo-weighted col-sum -> 32 partials/lane, transpose-reduce
  int c0 = cc * 128 + wn * 64;
  float q0 = resqc[b * HH + c0 + lo], q1 = resqc[b * HH + c0 + 32 + lo];
  float w0 = Wo[c0 + lo],             w1 = Wo[c0 + 32 + lo];
  float v[32];
#pragma unroll
  for (int m = 0; m < 2; ++m)
#pragma unroll
    for (int r = 0; r < 16; ++r)
      v[m * 16 + r] = w0 * fast_tanh(acc[m][0][r] + q0)
                    + w1 * fast_tanh(acc[m][1][r] + q1);
  // transpose-reduce over 32 col-lanes: lane lo ends with the full sum of value lo
#pragma unroll
  for (int sdist = 16; sdist >= 1; sdist >>= 1) {
#pragma unroll
    for (int i = 0; i < sdist; ++i) {
      float a = v[i], c = v[i + sdist];
      float keep = (lo & sdist) ? c : a;
      float send = (lo & sdist) ? a : c;
      v[i] = keep + __shfl_xor(send, sdist, 64);
    }
  }
  int rr = lo & 15;
  int row_local = (lo >> 4) * 32 + (rr & 3) + 8 * (rr >> 2) + 4 * hi;  // C/D row map
  atomicAdd(&logit[rb * 128 + wm * 64 + row_local], v[0]);
}

// ---------------- weights: mask*exp(logit+bo), normalize over L ----------------
__global__ __launch_bounds__(256) void k_weights(const float* __restrict__ mask,
                                                 const float* __restrict__ bo,
                                                 const float* __restrict__ logit,
                                                 float* __restrict__ wout) {
  __shared__ float red[4];
  int b = blockIdx.x, t = threadIdx.x;
  float bov = bo[0];
  float w[8];
  float s = 0.f;
#pragma unroll
  for (int i = 0; i < 8; ++i) {
    int l = t + 256 * i;
    float e = mask[b * LL + l] * __expf(logit[b * LL + l] + bov);
    w[i] = e; s += e;
  }
#pragma unroll
  for (int m = 32; m >= 1; m >>= 1) s += __shfl_xor(s, m, 64);
  int wave = t >> 6, lane = t & 63;
  if (lane == 0) red[wave] = s;
  __syncthreads();
  float inv = 1.0f / (red[0] + red[1] + red[2] + red[3] + 1e-5f);
#pragma unroll
  for (int i = 0; i < 8; ++i) wout[b * LL + t + 256 * i] = w[i] * inv;
}

// ---------------- output from packed ctx: out[b][c] = sum_l w[b][l]*A[l][c] ----
// 512 blocks = 32 b x 4 ks-quarters x 4 L-chunks; 512 thr. Thread owns 16 cols,
// loops 16 tiles; shfl-reduce over lo; lane lo==0 atomicAdd (out zeroed).
__global__ __launch_bounds__(512) void k_output_pk(const uint4* __restrict__ apk,
                                                   const float* __restrict__ wout,
                                                   float* __restrict__ out) {
  int bid = blockIdx.x;
  int b = bid >> 4, q = (bid >> 2) & 3, lc = bid & 3;
  int t = threadIdx.x;
  int lane = t & 63, ks = q * 8 + (t >> 6);
  int lo = lane & 31, hi = lane >> 5;
  const uint4* pa = apk + (size_t)(b * 64 + lc * 16) * 2048 + (size_t)ks * 64 + lane;
  const float* wp = wout + b * LL + lc * 512 + lo;
  float a8[8] = {0,0,0,0,0,0,0,0};
#pragma unroll 4
  for (int gg = 0; gg < 16; ++gg) {
    uint4 u = pa[(size_t)gg * 2048];
    float w = wp[gg * 32];
    unsigned int uu[4] = {u.x, u.y, u.z, u.w};
#pragma unroll
    for (int j = 0; j < 4; ++j) {
      a8[2 * j]     += w * __uint_as_float(uu[j] << 16);
      a8[2 * j + 1] += w * __uint_as_float(uu[j] & 0xffff0000u);
    }
  }
#pragma unroll
  for (int m = 1; m <= 16; m <<= 1)
#pragma unroll
    for (int j = 0; j < 8; ++j) a8[j] += __shfl_xor(a8[j], m, 64);
  if (lo == 0) {
#pragma unroll
    for (int j = 0; j < 8; ++j) atomicAdd(&out[b * CH + ks * 16 + hi * 8 + j], a8[j]);
  }
}

extern "C" void kernel_launch(void* const* d_in, const int* in_sizes, int n_in,
                              void* d_out, int out_size, void* d_ws, size_t ws_size,
                              hipStream_t stream) {
  const float* query = (const float*)d_in[0];
  const float* ctx   = (const float*)d_in[1];
  const float* mask  = (const float*)d_in[2];
  const float* Wq    = (const float*)d_in[3];
  const float* Wc    = (const float*)d_in[4];
  const float* bc    = (const float*)d_in[5];
  const float* Wo    = (const float*)d_in[6];
  const float* bo    = (const float*)d_in[7];
  float* out = (float*)d_out;

  uint4* wcbp  = (uint4*)d_ws;                                    // 1 MB packed bf16 Wc
  float* resqc = (float*)((char*)d_ws + (1 << 20));               // 128 KB
  float* logit = (float*)((char*)d_ws + (1 << 20) + (1 << 17));   // 256 KB
  uint4* apk   = (uint4*)((char*)d_ws + (2 << 20));               // 64 MB packed bf16 ctx
  float* wout = out + NB * CH;                                    // final weights slot

  hipMemsetAsync(out, 0, NB * CH * sizeof(float), stream);
  hipMemsetAsync(logit, 0, NB * LL * sizeof(float), stream);
  k_resqc<<<128, 256, 0, stream>>>(query, Wq, bc, resqc);
  k_pack_wc<<<256, 256, 0, stream>>>(Wc, wcbp);
  k_pack_ctx_t<<<2048, 256, 0, stream>>>(ctx, apk);
  k_logits_pk3<<<4096, 256, 0, stream>>>(apk, wcbp, resqc, Wo, logit);
  k_weights<<<32, 256, 0, stream>>>(mask, bo, logit, wout);
  k_output_pk<<<512, 512, 0, stream>>>(apk, wout, out);
}

// Round 12
// 157.083 us; speedup vs baseline: 1.1748x; 1.0024x over previous
//
#include <hip/hip_runtime.h>

#define NB 32
#define LL 2048
#define CH 512
#define BQ 512
#define HH 1024

typedef __attribute__((ext_vector_type(8))) short bf16x8;
typedef __attribute__((ext_vector_type(16))) float f32x16;

__device__ __forceinline__ unsigned int cvt_pk_bf16(float a, float b) {
  unsigned int r;
  asm("v_cvt_pk_bf16_f32 %0, %1, %2" : "=v"(r) : "v"(a), "v"(b));
  return r;   // lo16 = bf16(a), hi16 = bf16(b)
}

__device__ __forceinline__ float fast_tanh(float x) {
  float e = __builtin_amdgcn_exp2f(x * 2.885390081777927f);
  return 1.0f - 2.0f * __builtin_amdgcn_rcpf(e + 1.0f);
}

// ================ fused prep ================
// [0,2048)    : pack 32 ctx rows -> apk (A-frag order) via LDS transpose
// [2048,2304) : pack Wc -> wcbp (B-frag order)
// [2304,2432) : res_qc = query@Wq^T + bc
// [2432,2448) : zero logit (65536 f32)
// 2448        : zero out (16384 f32)
__global__ __launch_bounds__(256) void k_prep(const float* __restrict__ ctx,
                                              uint4* __restrict__ apk,
                                              const float* __restrict__ Wc,
                                              uint4* __restrict__ wcbp,
                                              const float* __restrict__ query,
                                              const float* __restrict__ Wq,
                                              const float* __restrict__ bc,
                                              float* __restrict__ resqc,
                                              float* __restrict__ logit,
                                              float* __restrict__ out) {
  __shared__ unsigned short slds[32 * 520];   // 33280 B
  int bid = blockIdx.x, t = threadIdx.x;
  if (bid < 2048) {
    int g = bid;
    const float4* src = (const float4*)(ctx + (size_t)g * 32 * CH);
#pragma unroll
    for (int i = 0; i < 16; ++i) {
      int f = i * 256 + t;           // 4096 float4s
      int row = f >> 7, c4 = f & 127;
      float4 v = src[f];
      uint2 w;
      w.x = cvt_pk_bf16(v.x, v.y);
      w.y = cvt_pk_bf16(v.z, v.w);
      *(uint2*)(slds + row * 520 + c4 * 4) = w;
    }
    __syncthreads();
    uint4* dst = apk + (size_t)g * 2048;
#pragma unroll
    for (int i = 0; i < 8; ++i) {
      int idx2 = i * 256 + t;        // 2048 chunks = 32 ks x 64 lanes
      int ks = idx2 >> 6, lane2 = idx2 & 63;
      int lo = lane2 & 31, hi = lane2 >> 5;
      dst[idx2] = *(const uint4*)(slds + lo * 520 + ks * 16 + hi * 8);
    }
  } else if (bid < 2304) {
    int gid = (bid - 2048) * 256 + t;   // 65536
    int lane = gid & 63, ks = (gid >> 6) & 31, cg = gid >> 11;
    int lo = lane & 31, hi = lane >> 5;
    const float4* s = (const float4*)(Wc + (size_t)(cg * 32 + lo) * CH + hi * 8 + ks * 16);
    float4 v0 = s[0], v1 = s[1];
    uint4 p;
    p.x = cvt_pk_bf16(v0.x, v0.y);
    p.y = cvt_pk_bf16(v0.z, v0.w);
    p.z = cvt_pk_bf16(v1.x, v1.y);
    p.w = cvt_pk_bf16(v1.z, v1.w);
    wcbp[gid] = p;
  } else if (bid < 2432) {
    int gid = (bid - 2304) * 256 + t;   // 32768
    int b = gid >> 10, h = gid & 1023;
    const float4* q4 = (const float4*)(query + (size_t)b * BQ);
    const float4* w4 = (const float4*)(Wq + (size_t)h * BQ);
    float acc = 0.f;
#pragma unroll 4
    for (int i = 0; i < BQ / 4; ++i) {
      float4 a = q4[i], w = w4[i];
      acc += a.x * w.x + a.y * w.y + a.z * w.z + a.w * w.w;
    }
    resqc[gid] = acc + bc[h];
  } else if (bid < 2448) {
    float4* p = (float4*)logit + (bid - 2432) * 1024 + t;
#pragma unroll
    for (int i = 0; i < 4; ++i) p[i * 256] = (float4){0, 0, 0, 0};
  } else {
    float4* p = (float4*)out + t;
#pragma unroll
    for (int i = 0; i < 16; ++i) p[i * 256] = (float4){0, 0, 0, 0};
  }
}

// ---------------- main GEMM+tanh+reduce: no LDS, no barriers, SALU addressing ----
// 4096 blocks x 256 thr (4 waves, 2M x 2N). Block = 128r x 128c; wave = 64r x 64c,
// acc[2][2]=64 AGPR, 3 waves/SIMD. All K-loop addresses = wave-uniform SGPR base
// (readfirstlane) + fixed per-lane voffset + imm -> saddr-form loads, ~0 VALU/ks.
__global__ __launch_bounds__(256, 3) void k_logits_pk3(const uint4* __restrict__ apk,
                                                       const uint4* __restrict__ bpk,
                                                       const float* __restrict__ resqc,
                                                       const float* __restrict__ Wo,
                                                       float* __restrict__ logit) {
  int bid = blockIdx.x;
  // XCD swizzle (4096%8==0, bijective): xcd owns 64 row-blocks; the 8 cc-chunks
  // of one rb are consecutive -> A tile stays hot in the XCD L2.
  int xcd = bid & 7, idx = bid >> 3;
  int rb = xcd * 64 + (idx >> 3);  // 512 row-blocks of 128 rows
  int cc = idx & 7;                // 8 col-chunks of 128
  int t = threadIdx.x;
  int wv = t >> 6, lane = t & 63;
  int wm = wv >> 1, wn = wv & 1;
  int lo = lane & 31, hi = lane >> 5;
  int b = rb >> 4;

  // wave-uniform bases -> saddr-form global loads
  int wmu = __builtin_amdgcn_readfirstlane(wm);
  int wnu = __builtin_amdgcn_readfirstlane(wn);
  const char* a0 = (const char*)(apk + (size_t)(rb * 4 + wmu * 2) * 2048);
  const char* a1 = a0 + 32768;
  const char* b0 = (const char*)(bpk + (size_t)(cc * 4 + wnu * 2) * 2048);
  const char* b1 = b0 + 32768;
  const unsigned vo = lane * 16;   // fixed per-lane byte offset

  f32x16 acc[2][2];
#pragma unroll
  for (int m = 0; m < 2; ++m)
#pragma unroll
    for (int n = 0; n < 2; ++n) acc[m][n] = (f32x16){0,0,0,0,0,0,0,0,0,0,0,0,0,0,0,0};

  for (int kg = 0; kg < 8; ++kg) {   // 8 groups x 4 ks; imm offsets j*1024 <= 3072
#pragma unroll
    for (int j = 0; j < 4; ++j) {
      uint4 ua0 = *(const uint4*)(a0 + vo + j * 1024);
      uint4 ua1 = *(const uint4*)(a1 + vo + j * 1024);
      uint4 ub0 = *(const uint4*)(b0 + vo + j * 1024);
      uint4 ub1 = *(const uint4*)(b1 + vo + j * 1024);
      bf16x8 fa0, fa1, fb0, fb1;
      __builtin_memcpy(&fa0, &ua0, 16);
      __builtin_memcpy(&fa1, &ua1, 16);
      __builtin_memcpy(&fb0, &ub0, 16);
      __builtin_memcpy(&fb1, &ub1, 16);
      acc[0][0] = __builtin_amdgcn_mfma_f32_32x32x16_bf16(fa0, fb0, acc[0][0], 0, 0, 0);
      acc[0][1] = __builtin_amdgcn_mfma_f32_32x32x16_bf16(fa0, fb1, acc[0][1], 0, 0, 0);
      acc[1][0] = __builtin_amdgcn_mfma_f32_32x32x16_bf16(fa1, fb0, acc[1][0], 0, 0, 0);
      acc[1][1] = __builtin_amdgcn_mfma_f32_32x32x16_bf16(fa1, fb1, acc[1][1], 0, 0, 0);
    }
    a0 += 4096; a1 += 4096; b0 += 4096; b1 += 4096;   // uniform -> SALU bumps
  }

  // epilogue: tanh + Wo-weighted col-sum -> 32 partials/lane, transpose-reduce
  int c0 = cc * 128 + wn * 64;
  float q0 = resqc[b * HH + c0 + lo], q1 = resqc[b * HH + c0 + 32 + lo];
  float w0 = Wo[c0 + lo],             w1 = Wo[c0 + 32 + lo];
  float v[32];
#pragma unroll
  for (int m = 0; m < 2; ++m)
#pragma unroll
    for (int r = 0; r < 16; ++r)
      v[m * 16 + r] = w0 * fast_tanh(acc[m][0][r] + q0)
                    + w1 * fast_tanh(acc[m][1][r] + q1);
  // transpose-reduce over 32 col-lanes: lane lo ends with the full sum of value lo
#pragma unroll
  for (int sdist = 16; sdist >= 1; sdist >>= 1) {
#pragma unroll
    for (int i = 0; i < sdist; ++i) {
      float a = v[i], c = v[i + sdist];
      float keep = (lo & sdist) ? c : a;
      float send = (lo & sdist) ? a : c;
      v[i] = keep + __shfl_xor(send, sdist, 64);
    }
  }
  int rr = lo & 15;
  int row_local = (lo >> 4) * 32 + (rr & 3) + 8 * (rr >> 2) + 4 * hi;  // C/D row map
  atomicAdd(&logit[rb * 128 + wm * 64 + row_local], v[0]);
}

// ---------------- weights: mask*exp(logit+bo), normalize over L ----------------
__global__ __launch_bounds__(256) void k_weights(const float* __restrict__ mask,
                                                 const float* __restrict__ bo,
                                                 const float* __restrict__ logit,
                                                 float* __restrict__ wout) {
  __shared__ float red[4];
  int b = blockIdx.x, t = threadIdx.x;
  float bov = bo[0];
  float w[8];
  float s = 0.f;
#pragma unroll
  for (int i = 0; i < 8; ++i) {
    int l = t + 256 * i;
    float e = mask[b * LL + l] * __expf(logit[b * LL + l] + bov);
    w[i] = e; s += e;
  }
#pragma unroll
  for (int m = 32; m >= 1; m >>= 1) s += __shfl_xor(s, m, 64);
  int wave = t >> 6, lane = t & 63;
  if (lane == 0) red[wave] = s;
  __syncthreads();
  float inv = 1.0f / (red[0] + red[1] + red[2] + red[3] + 1e-5f);
#pragma unroll
  for (int i = 0; i < 8; ++i) wout[b * LL + t + 256 * i] = w[i] * inv;
}

// ---------------- output from packed ctx: out[b][c] = sum_l w[b][l]*A[l][c] ----
__global__ __launch_bounds__(512) void k_output_pk(const uint4* __restrict__ apk,
                                                   const float* __restrict__ wout,
                                                   float* __restrict__ out) {
  int bid = blockIdx.x;
  int b = bid >> 4, q = (bid >> 2) & 3, lc = bid & 3;
  int t = threadIdx.x;
  int lane = t & 63, ks = q * 8 + (t >> 6);
  int lo = lane & 31, hi = lane >> 5;
  const uint4* pa = apk + (size_t)(b * 64 + lc * 16) * 2048 + (size_t)ks * 64 + lane;
  const float* wp = wout + b * LL + lc * 512 + lo;
  float a8[8] = {0,0,0,0,0,0,0,0};
#pragma unroll 4
  for (int gg = 0; gg < 16; ++gg) {
    uint4 u = pa[(size_t)gg * 2048];
    float w = wp[gg * 32];
    unsigned int uu[4] = {u.x, u.y, u.z, u.w};
#pragma unroll
    for (int j = 0; j < 4; ++j) {
      a8[2 * j]     += w * __uint_as_float(uu[j] << 16);
      a8[2 * j + 1] += w * __uint_as_float(uu[j] & 0xffff0000u);
    }
  }
#pragma unroll
  for (int m = 1; m <= 16; m <<= 1)
#pragma unroll
    for (int j = 0; j < 8; ++j) a8[j] += __shfl_xor(a8[j], m, 64);
  if (lo == 0) {
#pragma unroll
    for (int j = 0; j < 8; ++j) atomicAdd(&out[b * CH + ks * 16 + hi * 8 + j], a8[j]);
  }
}

extern "C" void kernel_launch(void* const* d_in, const int* in_sizes, int n_in,
                              void* d_out, int out_size, void* d_ws, size_t ws_size,
                              hipStream_t stream) {
  const float* query = (const float*)d_in[0];
  const float* ctx   = (const float*)d_in[1];
  const float* mask  = (const float*)d_in[2];
  const float* Wq    = (const float*)d_in[3];
  const float* Wc    = (const float*)d_in[4];
  const float* bc    = (const float*)d_in[5];
  const float* Wo    = (const float*)d_in[6];
  const float* bo    = (const float*)d_in[7];
  float* out = (float*)d_out;

  uint4* wcbp  = (uint4*)d_ws;                                    // 1 MB packed bf16 Wc
  float* resqc = (float*)((char*)d_ws + (1 << 20));               // 128 KB
  float* logit = (float*)((char*)d_ws + (1 << 20) + (1 << 17));   // 256 KB
  uint4* apk   = (uint4*)((char*)d_ws + (2 << 20));               // 64 MB packed bf16 ctx
  float* wout = out + NB * CH;                                    // final weights slot

  k_prep<<<2449, 256, 0, stream>>>(ctx, apk, Wc, wcbp, query, Wq, bc, resqc, logit, out);
  k_logits_pk3<<<4096, 256, 0, stream>>>(apk, wcbp, resqc, Wo, logit);
  k_weights<<<32, 256, 0, stream>>>(mask, bo, logit, wout);
  k_output_pk<<<512, 512, 0, stream>>>(apk, wout, out);
}

// Round 13
// 125.595 us; speedup vs baseline: 1.4693x; 1.2507x over previous
//
#include <hip/hip_runtime.h>

#define NB 32
#define LL 2048
#define CH 512
#define BQ 512
#define HH 1024

typedef __attribute__((ext_vector_type(8))) short bf16x8;
typedef __attribute__((ext_vector_type(16))) float f32x16;

__device__ __forceinline__ unsigned int cvt_pk_bf16(float a, float b) {
  unsigned int r;
  asm("v_cvt_pk_bf16_f32 %0, %1, %2" : "=v"(r) : "v"(a), "v"(b));
  return r;   // lo16 = bf16(a), hi16 = bf16(b)
}

__device__ __forceinline__ float fast_tanh(float x) {
  float e = __builtin_amdgcn_exp2f(x * 2.885390081777927f);
  return 1.0f - 2.0f * __builtin_amdgcn_rcpf(e + 1.0f);
}

// ================ fused small prep ================
// [0,256)   : pack Wc -> wcbp (B-frag order, 65536 uint4)
// [256,384) : res_qc = query@Wq^T + bc (32768)
// [384,400) : zero logit (65536 f32)
// 400       : zero out (16384 f32)
__global__ __launch_bounds__(256) void k_prep(const float* __restrict__ Wc,
                                              uint4* __restrict__ wcbp,
                                              const float* __restrict__ query,
                                              const float* __restrict__ Wq,
                                              const float* __restrict__ bc,
                                              float* __restrict__ resqc,
                                              float* __restrict__ logit,
                                              float* __restrict__ out) {
  int bid = blockIdx.x, t = threadIdx.x;
  if (bid < 256) {
    int gid = bid * 256 + t;   // 65536 = 32 cg * 32 ks * 64 lanes
    int lane = gid & 63, ks = (gid >> 6) & 31, cg = gid >> 11;
    int lo = lane & 31, hi = lane >> 5;
    const float4* s = (const float4*)(Wc + (size_t)(cg * 32 + lo) * CH + hi * 8 + ks * 16);
    float4 v0 = s[0], v1 = s[1];
    uint4 p;
    p.x = cvt_pk_bf16(v0.x, v0.y);
    p.y = cvt_pk_bf16(v0.z, v0.w);
    p.z = cvt_pk_bf16(v1.x, v1.y);
    p.w = cvt_pk_bf16(v1.z, v1.w);
    wcbp[gid] = p;
  } else if (bid < 384) {
    int gid = (bid - 256) * 256 + t;   // 32768
    int b = gid >> 10, h = gid & 1023;
    const float4* q4 = (const float4*)(query + (size_t)b * BQ);
    const float4* w4 = (const float4*)(Wq + (size_t)h * BQ);
    float acc = 0.f;
#pragma unroll 4
    for (int i = 0; i < BQ / 4; ++i) {
      float4 a = q4[i], w = w4[i];
      acc += a.x * w.x + a.y * w.y + a.z * w.z + a.w * w.w;
    }
    resqc[gid] = acc + bc[h];
  } else if (bid < 400) {
    float4* p = (float4*)logit + (bid - 384) * 1024 + t;
#pragma unroll
    for (int i = 0; i < 4; ++i) p[i * 256] = (float4){0, 0, 0, 0};
  } else {
    float4* p = (float4*)out + t;
#pragma unroll
    for (int i = 0; i < 16; ++i) p[i * 256] = (float4){0, 0, 0, 0};
  }
}

// ---------------- main: one 64-row tile per block, A in LDS, 2 blocks/CU ----
// 2048 blocks = 32 b x 32 rowtiles x 2 N-halves; 512 thr (8 waves). Wave =
// 64r x 64c, acc[2][2]=64 AGPR -> 128-reg budget ok -> 4 waves/SIMD (2 blocks
// resident; cross-block stage/compute overlap). A: [64][520] bf16 LDS (r6
// layout, measured 0 conflicts). B: packed wcbp via saddr loads (L2-hot).
__global__ __launch_bounds__(512, 4) void k_logits_f(const float* __restrict__ ctx,
                                                     const uint4* __restrict__ bpk,
                                                     const float* __restrict__ resqc,
                                                     const float* __restrict__ Wo,
                                                     float* __restrict__ logit) {
  __shared__ unsigned short A[64 * 520];   // 66560 B

  const int t = threadIdx.x;
  const int bid = blockIdx.x;
  // XCD pair-swizzle (r3): both N-halves of one A-tile land adjacent on one XCD
  const int swz = (bid & 7) * 256 + (bid >> 3);
  const int lt = swz >> 1, nh = swz & 1;
  const int b = lt >> 5, row0 = (lt & 31) << 6;

  // stage A tile: 64 rows x 512 f32 -> bf16 LDS (coalesced; 16 float4/thread)
  const float4* src = (const float4*)(ctx + ((size_t)(b * LL + row0)) * CH);
#pragma unroll
  for (int i = 0; i < 16; ++i) {
    int f = i * 512 + t;
    int r = f >> 7, c4 = f & 127;
    float4 v = src[f];
    uint2 w;
    w.x = cvt_pk_bf16(v.x, v.y);
    w.y = cvt_pk_bf16(v.z, v.w);
    *(uint2*)(A + r * 520 + c4 * 4) = w;
  }
  __syncthreads();

  const int wv = t >> 6, lane = t & 63;
  const int lo = lane & 31, hi = lane >> 5;

  // wave-uniform B base -> saddr loads; fixed per-lane voffset
  const int wvu = __builtin_amdgcn_readfirstlane(wv);
  const char* b0 = (const char*)(bpk + (size_t)((nh * 16 + wvu * 2) * 32) * 64);
  const char* b1 = b0 + 32768;
  const unsigned vo = lane * 16;

  const char* a0 = (const char*)A + lo * 1040 + hi * 16;   // rows lo / lo+32

  f32x16 acc[2][2];
#pragma unroll
  for (int m = 0; m < 2; ++m)
#pragma unroll
    for (int n = 0; n < 2; ++n) acc[m][n] = (f32x16){0,0,0,0,0,0,0,0,0,0,0,0,0,0,0,0};

  for (int kg = 0; kg < 8; ++kg) {   // 8 groups x 4 ks
#pragma unroll
    for (int j = 0; j < 4; ++j) {
      uint4 ub0 = *(const uint4*)(b0 + vo + j * 1024);
      uint4 ub1 = *(const uint4*)(b1 + vo + j * 1024);
      bf16x8 fa0 = *(const bf16x8*)(a0 + kg * 128 + j * 32);
      bf16x8 fa1 = *(const bf16x8*)(a0 + 33280 + kg * 128 + j * 32);
      bf16x8 fb0, fb1;
      __builtin_memcpy(&fb0, &ub0, 16);
      __builtin_memcpy(&fb1, &ub1, 16);
      acc[0][0] = __builtin_amdgcn_mfma_f32_32x32x16_bf16(fa0, fb0, acc[0][0], 0, 0, 0);
      acc[0][1] = __builtin_amdgcn_mfma_f32_32x32x16_bf16(fa0, fb1, acc[0][1], 0, 0, 0);
      acc[1][0] = __builtin_amdgcn_mfma_f32_32x32x16_bf16(fa1, fb0, acc[1][0], 0, 0, 0);
      acc[1][1] = __builtin_amdgcn_mfma_f32_32x32x16_bf16(fa1, fb1, acc[1][1], 0, 0, 0);
    }
    b0 += 4096; b1 += 4096;   // uniform SALU bumps
  }

  // epilogue: tanh + Wo-weighted col-sum -> transpose-reduce -> global atomics
  const int c0 = nh * 512 + wv * 64;
  float q0 = resqc[b * HH + c0 + lo], q1 = resqc[b * HH + c0 + 32 + lo];
  float w0 = Wo[c0 + lo],             w1 = Wo[c0 + 32 + lo];
  float v[32];
#pragma unroll
  for (int m = 0; m < 2; ++m)
#pragma unroll
    for (int r = 0; r < 16; ++r)
      v[m * 16 + r] = w0 * fast_tanh(acc[m][0][r] + q0)
                    + w1 * fast_tanh(acc[m][1][r] + q1);
  // transpose-reduce over 32 col-lanes: lane lo ends with the full sum of value lo
#pragma unroll
  for (int sdist = 16; sdist >= 1; sdist >>= 1) {
#pragma unroll
    for (int i = 0; i < sdist; ++i) {
      float a = v[i], c = v[i + sdist];
      float keep = (lo & sdist) ? c : a;
      float send = (lo & sdist) ? a : c;
      v[i] = keep + __shfl_xor(send, sdist, 64);
    }
  }
  int rr = lo & 15;
  int row_local = (lo >> 4) * 32 + (rr & 3) + 8 * (rr >> 2) + 4 * hi;  // C/D row map
  atomicAdd(&logit[(size_t)b * LL + row0 + row_local], v[0]);
}

// ---------------- weights: mask*exp(logit+bo), normalize over L ----------------
__global__ __launch_bounds__(256) void k_weights(const float* __restrict__ mask,
                                                 const float* __restrict__ bo,
                                                 const float* __restrict__ logit,
                                                 float* __restrict__ wout) {
  __shared__ float red[4];
  int b = blockIdx.x, t = threadIdx.x;
  float bov = bo[0];
  float w[8];
  float s = 0.f;
#pragma unroll
  for (int i = 0; i < 8; ++i) {
    int l = t + 256 * i;
    float e = mask[b * LL + l] * __expf(logit[b * LL + l] + bov);
    w[i] = e; s += e;
  }
#pragma unroll
  for (int m = 32; m >= 1; m >>= 1) s += __shfl_xor(s, m, 64);
  int wave = t >> 6, lane = t & 63;
  if (lane == 0) red[wave] = s;
  __syncthreads();
  float inv = 1.0f / (red[0] + red[1] + red[2] + red[3] + 1e-5f);
#pragma unroll
  for (int i = 0; i < 8; ++i) wout[b * LL + t + 256 * i] = w[i] * inv;
}

// ---------------- output[b][c] = sum_l weights[b][l] * ctx[b][l][c] (ctx in L3) ----
__global__ __launch_bounds__(256) void k_output_f32(const float* __restrict__ ctx,
                                                    const float* __restrict__ weights,
                                                    float* __restrict__ out) {
  __shared__ float wl[128];
  int bid = blockIdx.x;            // 512 = 32 b * 16 chunks
  int b = bid >> 4, chunk = bid & 15;
  int t = threadIdx.x;
  int l0 = chunk * 128;
  if (t < 128) wl[t] = weights[b * LL + l0 + t];
  __syncthreads();
  const float2* c2 = (const float2*)(ctx + ((size_t)(b * LL + l0)) * CH) + t;
  float ax = 0.f, ay = 0.f;
#pragma unroll 4
  for (int l = 0; l < 128; ++l) {
    float wv = wl[l];
    float2 v = c2[(size_t)l * (CH / 2)];
    ax += wv * v.x; ay += wv * v.y;
  }
  atomicAdd(&out[b * CH + 2 * t], ax);
  atomicAdd(&out[b * CH + 2 * t + 1], ay);
}

extern "C" void kernel_launch(void* const* d_in, const int* in_sizes, int n_in,
                              void* d_out, int out_size, void* d_ws, size_t ws_size,
                              hipStream_t stream) {
  const float* query = (const float*)d_in[0];
  const float* ctx   = (const float*)d_in[1];
  const float* mask  = (const float*)d_in[2];
  const float* Wq    = (const float*)d_in[3];
  const float* Wc    = (const float*)d_in[4];
  const float* bc    = (const float*)d_in[5];
  const float* Wo    = (const float*)d_in[6];
  const float* bo    = (const float*)d_in[7];
  float* out = (float*)d_out;

  uint4* wcbp  = (uint4*)d_ws;                                    // 1 MB packed bf16 Wc
  float* resqc = (float*)((char*)d_ws + (1 << 20));               // 128 KB
  float* logit = (float*)((char*)d_ws + (1 << 20) + (1 << 17));   // 256 KB
  float* wout = out + NB * CH;                                    // final weights slot

  k_prep<<<401, 256, 0, stream>>>(Wc, wcbp, query, Wq, bc, resqc, logit, out);
  k_logits_f<<<2048, 512, 0, stream>>>(ctx, wcbp, resqc, Wo, logit);
  k_weights<<<32, 256, 0, stream>>>(mask, bo, logit, wout);
  k_output_f32<<<512, 256, 0, stream>>>(ctx, wout, out);
}